// Round 11
// baseline (73.765 us; speedup 1.0000x reference)
//
#include <hip/hip_runtime.h>

// Actor MLP, B=262144 rows, fp32 in/out. Phases 2+3 on MFMA (16x16x32 bf16).
// R10 passed (103us prof, absmax 0.031, margin 5.3x). R11: drop A-side lo
// splits (s, z stay bf16-rounded; W3/W4 keep hi+lo B-side correction ->
// predicted absmax ~0.06-0.09 < 0.165). MFMA 288->192/block, LDS 16->8KB,
// staging VALU halves. Occupancy: __launch_bounds__(256,6) -> 6 blocks/CU,
// 24 waves/CU (75%), reg cap 85 > live ~70 (R8 spill cliff was cap 64).

typedef float f4v  __attribute__((ext_vector_type(4)));
typedef float f16v __attribute__((ext_vector_type(16)));
typedef short s8v  __attribute__((ext_vector_type(8)));
typedef short s4v  __attribute__((ext_vector_type(4)));

constexpr int NG = 14, GI = 9, FH = 128, AD = 15;

__device__ __forceinline__ unsigned short f2bf(float f) {
    unsigned u = __builtin_bit_cast(unsigned, f);
    return (unsigned short)((u + 0x7fffu + ((u >> 16) & 1u)) >> 16);
}
__device__ __forceinline__ float bf2f(unsigned short h) {
    return __builtin_bit_cast(float, (unsigned)h << 16);
}
__device__ __forceinline__ f4v load4u(const float* p) {
    f4v v; __builtin_memcpy(&v, p, 16); return v;
}

// Pack W3 (57x128, K pad->64) and W4 (128x30, N pad->32) into per-lane
// B-fragment order: idx = ((kt*NT + nt)*64 + lane)*8 + j, element
// k = kt*32 + (lane>>4)*8 + j, n = nt*16 + (lane&15). hi/lo split-bf16.
__global__ void pack_kernel(const float* __restrict__ W3,
                            const float* __restrict__ W4,
                            unsigned short* __restrict__ pk) {
    unsigned short* W3h = pk;            // 8192 elems
    unsigned short* W3l = pk + 8192;     // 8192
    unsigned short* W4h = pk + 16384;    // 4096
    unsigned short* W4l = pk + 20480;    // 4096
    int t = blockIdx.x * 256 + threadIdx.x;
    if (t < 8192) {
        int j = t & 7, l = (t >> 3) & 63, nt = (t >> 9) & 7, kt = t >> 12;
        int k = kt * 32 + (l >> 4) * 8 + j, n = nt * 16 + (l & 15);
        float v = (k < 57) ? W3[k * FH + n] : 0.f;
        unsigned short h = f2bf(v);
        W3h[t] = h;
        W3l[t] = f2bf(v - bf2f(h));
    }
    if (t < 4096) {
        int j = t & 7, l = (t >> 3) & 63, nt = (t >> 9) & 1, kt = t >> 10;
        int k = kt * 32 + (l >> 4) * 8 + j, n = nt * 16 + (l & 15);
        float v = (n < 30) ? W4[k * 30 + n] : 0.f;
        unsigned short h = f2bf(v);
        W4h[t] = h;
        W4l[t] = f2bf(v - bf2f(h));
    }
}

__global__ __launch_bounds__(256, 6) void actor_fused(
    const float* __restrict__ x,     // [B,126]
    const float* __restrict__ sale,  // [B,1]
    const float* __restrict__ W1,    // [9,16]
    const float* __restrict__ b1,    // [16]
    const float* __restrict__ W2,    // [16,4]
    const float* __restrict__ b2,    // [4]
    const float* __restrict__ b3,    // [128]
    const float* __restrict__ b4,    // [30]
    const unsigned short* __restrict__ pk,
    float* __restrict__ om, float* __restrict__ os)
{
    // 8 KB, aliased in time:
    //   phase 1/2: s_hi [64 rows][64 k] bf16 (XOR-swizzled rows)
    //   phase 3  : z_hi [32 rows][128 k] bf16
    __shared__ unsigned short sh[4096];

    const int tid  = threadIdx.x;
    const int wv   = __builtin_amdgcn_readfirstlane(tid >> 6);  // wave 0..3
    const int lane = tid & 63;
    const int r    = lane;                 // row within block (phase 1)
    const int row0 = blockIdx.x * 64;

    // ---------------- phase 1: VALU, groups split (4,4,3,3) ----------------
    const int gbase = __builtin_amdgcn_readfirstlane(4 * wv - (wv == 3 ? 1 : 0));
    const f16v* w1v = (const f16v*)W1;
    const f4v*  w2v = (const f4v*)W2;
    const f16v  b1v = *(const f16v*)b1;
    const f4v   b2v = *(const f4v*)b2;
    const float* xr = x + (size_t)(row0 + r) * (NG * GI);

    auto do_group = [&](int gg) {
        const float* xg = xr + gg * GI;
        f4v ca = load4u(xg), cb = load4u(xg + 4);
        float cs = xg[8];
        f16v h = b1v;
        h += ca[0]*w1v[0]; h += ca[1]*w1v[1]; h += ca[2]*w1v[2]; h += ca[3]*w1v[3];
        h += cb[0]*w1v[4]; h += cb[1]*w1v[5]; h += cb[2]*w1v[6]; h += cb[3]*w1v[7];
        h += cs*w1v[8];
        h = __builtin_elementwise_max(h, (f16v)0.f);
        f4v s = b2v;
        s += h[0]*w2v[0];  s += h[1]*w2v[1];  s += h[2]*w2v[2];  s += h[3]*w2v[3];
        s += h[4]*w2v[4];  s += h[5]*w2v[5];  s += h[6]*w2v[6];  s += h[7]*w2v[7];
        s += h[8]*w2v[8];  s += h[9]*w2v[9];  s += h[10]*w2v[10]; s += h[11]*w2v[11];
        s += h[12]*w2v[12]; s += h[13]*w2v[13]; s += h[14]*w2v[14]; s += h[15]*w2v[15];
        s = __builtin_elementwise_max(s, (f4v)0.f);
        s4v hi = (s4v){(short)f2bf(s[0]), (short)f2bf(s[1]),
                       (short)f2bf(s[2]), (short)f2bf(s[3])};
        int byt = (r * 128 + gg * 8) ^ ((r & 7) << 4);   // k = gg*4 -> byte gg*8
        *(s4v*)((char*)sh + byt) = hi;
    };
    if (wv < 2) { do_group(gbase+0); do_group(gbase+1); do_group(gbase+2); do_group(gbase+3); }
    else        { do_group(gbase+0); do_group(gbase+1); do_group(gbase+2); }
    if (wv == 3) {
        float sv = sale[row0 + r];
        int byt = (r * 128 + 112) ^ ((r & 7) << 4);      // k=56
        *(unsigned short*)((char*)sh + byt) = f2bf(sv);
        #pragma unroll
        for (int kk = 57; kk < 64; ++kk) {               // zero K-pad
            int bb = (r * 128 + kk * 2) ^ ((r & 7) << 4);
            *(unsigned short*)((char*)sh + bb) = 0;
        }
    }
    __syncthreads();

    // ---------------- phase 2: z[64,128] = s[64,64] @ W3  (MFMA) ----------
    const s8v* W3hv = (const s8v*)pk;
    const s8v* W3lv = (const s8v*)(pk + 8192);
    s8v bh[2][2], bl[2][2];
    #pragma unroll
    for (int kt = 0; kt < 2; ++kt)
        #pragma unroll
        for (int ntl = 0; ntl < 2; ++ntl) {
            int nt = 2 * wv + ntl;
            bh[kt][ntl] = W3hv[(kt * 8 + nt) * 64 + lane];
            bl[kt][ntl] = W3lv[(kt * 8 + nt) * 64 + lane];
        }
    f4v acc[4][2];
    #pragma unroll
    for (int ntl = 0; ntl < 2; ++ntl) {
        float bv = b3[32 * wv + ntl * 16 + (lane & 15)];
        #pragma unroll
        for (int mt = 0; mt < 4; ++mt) acc[mt][ntl] = (f4v){bv, bv, bv, bv};
    }
    #pragma unroll
    for (int kt = 0; kt < 2; ++kt) {
        s8v ah[4];
        #pragma unroll
        for (int mt = 0; mt < 4; ++mt) {
            int rr = mt * 16 + (lane & 15);
            int byt = (rr * 128 + kt * 64 + (lane >> 4) * 16) ^ ((rr & 7) << 4);
            ah[mt] = *(const s8v*)((char*)sh + byt);
        }
        #pragma unroll
        for (int mt = 0; mt < 4; ++mt)
            #pragma unroll
            for (int ntl = 0; ntl < 2; ++ntl) {
                acc[mt][ntl] = __builtin_amdgcn_mfma_f32_16x16x32_bf16(ah[mt], bh[kt][ntl], acc[mt][ntl], 0, 0, 0);
                acc[mt][ntl] = __builtin_amdgcn_mfma_f32_16x16x32_bf16(ah[mt], bl[kt][ntl], acc[mt][ntl], 0, 0, 0);
            }
    }

    // ------- phase 3: out[64,30] = relu(z)[64,128] @ W4, in two row-halves --
    const s8v* W4hv = (const s8v*)(pk + 16384);
    const s8v* W4lv = (const s8v*)(pk + 20480);
    const int mtt  = __builtin_amdgcn_readfirstlane(wv >> 1);
    const int ntt  = __builtin_amdgcn_readfirstlane(wv & 1);
    const int ocol = ntt * 16 + (lane & 15);
    const float b4i = (ocol < 30) ? b4[ocol] : 0.f;

    #pragma unroll
    for (int half = 0; half < 2; ++half) {
        __syncthreads();   // h0: all phase-2 s-reads done; h1: h0 z-reads done
        // stage relu(z) rows [32*half, 32*half+32) as bf16 (hi only)
        #pragma unroll
        for (int mtl = 0; mtl < 2; ++mtl) {
            const int mt = 2 * half + mtl;
            #pragma unroll
            for (int ntl = 0; ntl < 2; ++ntl) {
                const int col = 32 * wv + ntl * 16 + (lane & 15);
                #pragma unroll
                for (int i = 0; i < 4; ++i) {
                    int rowl = mtl * 16 + (lane >> 4) * 4 + i;   // m89 C/D map
                    float v = fmaxf(acc[mt][ntl][i], 0.f);
                    int byt = (rowl * 256 + col * 2) ^ ((rowl & 7) << 4);
                    *(unsigned short*)((char*)sh + byt) = f2bf(v);
                }
            }
        }
        __syncthreads();
        f4v oa = (f4v){b4i, b4i, b4i, b4i};
        #pragma unroll
        for (int kt = 0; kt < 4; ++kt) {
            int rr = mtt * 16 + (lane & 15);
            int byt = (rr * 256 + kt * 64 + (lane >> 4) * 16) ^ ((rr & 7) << 4);
            s8v zh = *(const s8v*)((char*)sh + byt);
            s8v wh = W4hv[(kt * 2 + ntt) * 64 + lane];
            s8v wl = W4lv[(kt * 2 + ntt) * 64 + lane];
            oa = __builtin_amdgcn_mfma_f32_16x16x32_bf16(zh, wh, oa, 0, 0, 0);
            oa = __builtin_amdgcn_mfma_f32_16x16x32_bf16(zh, wl, oa, 0, 0, 0);
        }
        #pragma unroll
        for (int i = 0; i < 4; ++i) {
            int grow = row0 + half * 32 + mtt * 16 + (lane >> 4) * 4 + i;
            float v = oa[i];
            if (ocol < AD) {
                float tc = fminf(fmaxf(v, -20.f), 20.f);
                float e = __expf(2.f * tc);
                om[(size_t)grow * AD + ocol] = (e - 1.f) / (e + 1.f);
            } else if (ocol < 2 * AD) {
                os[(size_t)grow * AD + (ocol - AD)] = __expf(v);
            }
        }
    }
}

extern "C" void kernel_launch(void* const* d_in, const int* in_sizes, int n_in,
                              void* d_out, int out_size, void* d_ws, size_t ws_size,
                              hipStream_t stream) {
    const float* x    = (const float*)d_in[0];
    const float* sale = (const float*)d_in[1];
    const float* W1   = (const float*)d_in[2];
    const float* b1   = (const float*)d_in[3];
    const float* W2   = (const float*)d_in[4];
    const float* b2   = (const float*)d_in[5];
    const float* W3   = (const float*)d_in[6];
    const float* b3   = (const float*)d_in[7];
    const float* W4   = (const float*)d_in[8];
    const float* b4   = (const float*)d_in[9];

    int B = in_sizes[1];                       // sale_predictions is [B,1]
    float* om = (float*)d_out;                 // action_mean flat [B*15]
    float* os = om + (size_t)B * AD;           // action_std  flat [B*15]
    unsigned short* pk = (unsigned short*)d_ws;  // 24576 bf16 = 48 KB

    pack_kernel<<<32, 256, 0, stream>>>(W3, W4, pk);
    actor_fused<<<B / 64, 256, 0, stream>>>(x, sale, W1, b1, W2, b2,
                                            b3, b4, pk, om, os);
}

// Round 12
// 66.270 us; speedup vs baseline: 1.1131x; 1.1131x over previous
//
#include <hip/hip_runtime.h>

// Actor MLP, B=262144 rows, fp32 in/out. Phases 2+3 on MFMA (16x16x32 bf16),
// A-side hi-only (s,z bf16-rounded), B-side (W3/W4) split hi+lo. 64 rows/blk,
// 4 waves. R11 post-mortem: (256,6)=85-reg cap re-spilled (WRITE 60MB @
// VGPR=40) - twice-measured cliff: this kernel family needs cap>=128.
// R12 = R11 structure + __launch_bounds__(256,4) (R10's proven no-spill).

typedef float f4v  __attribute__((ext_vector_type(4)));
typedef float f16v __attribute__((ext_vector_type(16)));
typedef short s8v  __attribute__((ext_vector_type(8)));
typedef short s4v  __attribute__((ext_vector_type(4)));

constexpr int NG = 14, GI = 9, FH = 128, AD = 15;

__device__ __forceinline__ unsigned short f2bf(float f) {
    unsigned u = __builtin_bit_cast(unsigned, f);
    return (unsigned short)((u + 0x7fffu + ((u >> 16) & 1u)) >> 16);
}
__device__ __forceinline__ float bf2f(unsigned short h) {
    return __builtin_bit_cast(float, (unsigned)h << 16);
}
__device__ __forceinline__ f4v load4u(const float* p) {
    f4v v; __builtin_memcpy(&v, p, 16); return v;
}

// Pack W3 (57x128, K pad->64) and W4 (128x30, N pad->32) into per-lane
// B-fragment order: idx = ((kt*NT + nt)*64 + lane)*8 + j, element
// k = kt*32 + (lane>>4)*8 + j, n = nt*16 + (lane&15). hi/lo split-bf16.
__global__ void pack_kernel(const float* __restrict__ W3,
                            const float* __restrict__ W4,
                            unsigned short* __restrict__ pk) {
    unsigned short* W3h = pk;            // 8192 elems
    unsigned short* W3l = pk + 8192;     // 8192
    unsigned short* W4h = pk + 16384;    // 4096
    unsigned short* W4l = pk + 20480;    // 4096
    int t = blockIdx.x * 256 + threadIdx.x;
    if (t < 8192) {
        int j = t & 7, l = (t >> 3) & 63, nt = (t >> 9) & 7, kt = t >> 12;
        int k = kt * 32 + (l >> 4) * 8 + j, n = nt * 16 + (l & 15);
        float v = (k < 57) ? W3[k * FH + n] : 0.f;
        unsigned short h = f2bf(v);
        W3h[t] = h;
        W3l[t] = f2bf(v - bf2f(h));
    }
    if (t < 4096) {
        int j = t & 7, l = (t >> 3) & 63, nt = (t >> 9) & 1, kt = t >> 10;
        int k = kt * 32 + (l >> 4) * 8 + j, n = nt * 16 + (l & 15);
        float v = (n < 30) ? W4[k * 30 + n] : 0.f;
        unsigned short h = f2bf(v);
        W4h[t] = h;
        W4l[t] = f2bf(v - bf2f(h));
    }
}

__global__ __launch_bounds__(256, 4) void actor_fused(
    const float* __restrict__ x,     // [B,126]
    const float* __restrict__ sale,  // [B,1]
    const float* __restrict__ W1,    // [9,16]
    const float* __restrict__ b1,    // [16]
    const float* __restrict__ W2,    // [16,4]
    const float* __restrict__ b2,    // [4]
    const float* __restrict__ b3,    // [128]
    const float* __restrict__ b4,    // [30]
    const unsigned short* __restrict__ pk,
    float* __restrict__ om, float* __restrict__ os)
{
    // 8 KB, aliased in time:
    //   phase 1/2: s_hi [64 rows][64 k] bf16 (XOR-swizzled rows)
    //   phase 3  : z_hi [32 rows][128 k] bf16
    __shared__ unsigned short sh[4096];

    const int tid  = threadIdx.x;
    const int wv   = __builtin_amdgcn_readfirstlane(tid >> 6);  // wave 0..3
    const int lane = tid & 63;
    const int r    = lane;                 // row within block (phase 1)
    const int row0 = blockIdx.x * 64;

    // ---------------- phase 1: VALU, groups split (4,4,3,3) ----------------
    const int gbase = __builtin_amdgcn_readfirstlane(4 * wv - (wv == 3 ? 1 : 0));
    const f16v* w1v = (const f16v*)W1;
    const f4v*  w2v = (const f4v*)W2;
    const f16v  b1v = *(const f16v*)b1;
    const f4v   b2v = *(const f4v*)b2;
    const float* xr = x + (size_t)(row0 + r) * (NG * GI);

    auto do_group = [&](int gg) {
        const float* xg = xr + gg * GI;
        f4v ca = load4u(xg), cb = load4u(xg + 4);
        float cs = xg[8];
        f16v h = b1v;
        h += ca[0]*w1v[0]; h += ca[1]*w1v[1]; h += ca[2]*w1v[2]; h += ca[3]*w1v[3];
        h += cb[0]*w1v[4]; h += cb[1]*w1v[5]; h += cb[2]*w1v[6]; h += cb[3]*w1v[7];
        h += cs*w1v[8];
        h = __builtin_elementwise_max(h, (f16v)0.f);
        f4v s = b2v;
        s += h[0]*w2v[0];  s += h[1]*w2v[1];  s += h[2]*w2v[2];  s += h[3]*w2v[3];
        s += h[4]*w2v[4];  s += h[5]*w2v[5];  s += h[6]*w2v[6];  s += h[7]*w2v[7];
        s += h[8]*w2v[8];  s += h[9]*w2v[9];  s += h[10]*w2v[10]; s += h[11]*w2v[11];
        s += h[12]*w2v[12]; s += h[13]*w2v[13]; s += h[14]*w2v[14]; s += h[15]*w2v[15];
        s = __builtin_elementwise_max(s, (f4v)0.f);
        s4v hi = (s4v){(short)f2bf(s[0]), (short)f2bf(s[1]),
                       (short)f2bf(s[2]), (short)f2bf(s[3])};
        int byt = (r * 128 + gg * 8) ^ ((r & 7) << 4);   // k = gg*4 -> byte gg*8
        *(s4v*)((char*)sh + byt) = hi;
    };
    if (wv < 2) { do_group(gbase+0); do_group(gbase+1); do_group(gbase+2); do_group(gbase+3); }
    else        { do_group(gbase+0); do_group(gbase+1); do_group(gbase+2); }
    if (wv == 3) {
        float sv = sale[row0 + r];
        int byt = (r * 128 + 112) ^ ((r & 7) << 4);      // k=56
        *(unsigned short*)((char*)sh + byt) = f2bf(sv);
        #pragma unroll
        for (int kk = 57; kk < 64; ++kk) {               // zero K-pad
            int bb = (r * 128 + kk * 2) ^ ((r & 7) << 4);
            *(unsigned short*)((char*)sh + bb) = 0;
        }
    }
    __syncthreads();

    // ---------------- phase 2: z[64,128] = s[64,64] @ W3  (MFMA) ----------
    const s8v* W3hv = (const s8v*)pk;
    const s8v* W3lv = (const s8v*)(pk + 8192);
    s8v bh[2][2], bl[2][2];
    #pragma unroll
    for (int kt = 0; kt < 2; ++kt)
        #pragma unroll
        for (int ntl = 0; ntl < 2; ++ntl) {
            int nt = 2 * wv + ntl;
            bh[kt][ntl] = W3hv[(kt * 8 + nt) * 64 + lane];
            bl[kt][ntl] = W3lv[(kt * 8 + nt) * 64 + lane];
        }
    f4v acc[4][2];
    #pragma unroll
    for (int ntl = 0; ntl < 2; ++ntl) {
        float bv = b3[32 * wv + ntl * 16 + (lane & 15)];
        #pragma unroll
        for (int mt = 0; mt < 4; ++mt) acc[mt][ntl] = (f4v){bv, bv, bv, bv};
    }
    #pragma unroll
    for (int kt = 0; kt < 2; ++kt) {
        s8v ah[4];
        #pragma unroll
        for (int mt = 0; mt < 4; ++mt) {
            int rr = mt * 16 + (lane & 15);
            int byt = (rr * 128 + kt * 64 + (lane >> 4) * 16) ^ ((rr & 7) << 4);
            ah[mt] = *(const s8v*)((char*)sh + byt);
        }
        #pragma unroll
        for (int mt = 0; mt < 4; ++mt)
            #pragma unroll
            for (int ntl = 0; ntl < 2; ++ntl) {
                acc[mt][ntl] = __builtin_amdgcn_mfma_f32_16x16x32_bf16(ah[mt], bh[kt][ntl], acc[mt][ntl], 0, 0, 0);
                acc[mt][ntl] = __builtin_amdgcn_mfma_f32_16x16x32_bf16(ah[mt], bl[kt][ntl], acc[mt][ntl], 0, 0, 0);
            }
    }

    // ------- phase 3: out[64,30] = relu(z)[64,128] @ W4, in two row-halves --
    const s8v* W4hv = (const s8v*)(pk + 16384);
    const s8v* W4lv = (const s8v*)(pk + 20480);
    const int mtt  = __builtin_amdgcn_readfirstlane(wv >> 1);
    const int ntt  = __builtin_amdgcn_readfirstlane(wv & 1);
    const int ocol = ntt * 16 + (lane & 15);
    const float b4i = (ocol < 30) ? b4[ocol] : 0.f;

    #pragma unroll
    for (int half = 0; half < 2; ++half) {
        __syncthreads();   // h0: all phase-2 s-reads done; h1: h0 z-reads done
        // stage relu(z) rows [32*half, 32*half+32) as bf16 (hi only)
        #pragma unroll
        for (int mtl = 0; mtl < 2; ++mtl) {
            const int mt = 2 * half + mtl;
            #pragma unroll
            for (int ntl = 0; ntl < 2; ++ntl) {
                const int col = 32 * wv + ntl * 16 + (lane & 15);
                #pragma unroll
                for (int i = 0; i < 4; ++i) {
                    int rowl = mtl * 16 + (lane >> 4) * 4 + i;   // m89 C/D map
                    float v = fmaxf(acc[mt][ntl][i], 0.f);
                    int byt = (rowl * 256 + col * 2) ^ ((rowl & 7) << 4);
                    *(unsigned short*)((char*)sh + byt) = f2bf(v);
                }
            }
        }
        __syncthreads();
        f4v oa = (f4v){b4i, b4i, b4i, b4i};
        #pragma unroll
        for (int kt = 0; kt < 4; ++kt) {
            int rr = mtt * 16 + (lane & 15);
            int byt = (rr * 256 + kt * 64 + (lane >> 4) * 16) ^ ((rr & 7) << 4);
            s8v zh = *(const s8v*)((char*)sh + byt);
            s8v wh = W4hv[(kt * 2 + ntt) * 64 + lane];
            s8v wl = W4lv[(kt * 2 + ntt) * 64 + lane];
            oa = __builtin_amdgcn_mfma_f32_16x16x32_bf16(zh, wh, oa, 0, 0, 0);
            oa = __builtin_amdgcn_mfma_f32_16x16x32_bf16(zh, wl, oa, 0, 0, 0);
        }
        #pragma unroll
        for (int i = 0; i < 4; ++i) {
            int grow = row0 + half * 32 + mtt * 16 + (lane >> 4) * 4 + i;
            float v = oa[i];
            if (ocol < AD) {
                float tc = fminf(fmaxf(v, -20.f), 20.f);
                float e = __expf(2.f * tc);
                om[(size_t)grow * AD + ocol] = (e - 1.f) / (e + 1.f);
            } else if (ocol < 2 * AD) {
                os[(size_t)grow * AD + (ocol - AD)] = __expf(v);
            }
        }
    }
}

extern "C" void kernel_launch(void* const* d_in, const int* in_sizes, int n_in,
                              void* d_out, int out_size, void* d_ws, size_t ws_size,
                              hipStream_t stream) {
    const float* x    = (const float*)d_in[0];
    const float* sale = (const float*)d_in[1];
    const float* W1   = (const float*)d_in[2];
    const float* b1   = (const float*)d_in[3];
    const float* W2   = (const float*)d_in[4];
    const float* b2   = (const float*)d_in[5];
    const float* W3   = (const float*)d_in[6];
    const float* b3   = (const float*)d_in[7];
    const float* W4   = (const float*)d_in[8];
    const float* b4   = (const float*)d_in[9];

    int B = in_sizes[1];                       // sale_predictions is [B,1]
    float* om = (float*)d_out;                 // action_mean flat [B*15]
    float* os = om + (size_t)B * AD;           // action_std  flat [B*15]
    unsigned short* pk = (unsigned short*)d_ws;  // 24576 bf16 = 48 KB

    pack_kernel<<<32, 256, 0, stream>>>(W3, W4, pk);
    actor_fused<<<B / 64, 256, 0, stream>>>(x, sale, W1, b1, W2, b2,
                                            b3, b4, pk, om, os);
}

// Round 13
// 55.693 us; speedup vs baseline: 1.3245x; 1.1899x over previous
//
#include <hip/hip_runtime.h>

// Actor MLP, B=262144 rows, fp32 in/out. Phases 2+3 on MFMA (16x16x32 bf16),
// A-side hi-only, B-side (W3/W4) split hi+lo. 64 rows/blk, 4 waves, (256,4).
// R12 post-mortem: MFMA/VALU/HBM all far from ceilings; wall is latency from
// uncoalesced per-row x loads (504B stride -> 64 lines per dwordx4).
// R13 single knob: coalesced bf16 staging of the x panel into LDS (16 KB);
// phase 1 reads x via ds_read_u16 (stride 63 words, odd -> conflict-free).

typedef float f4v  __attribute__((ext_vector_type(4)));
typedef float f16v __attribute__((ext_vector_type(16)));
typedef short s8v  __attribute__((ext_vector_type(8)));
typedef short s4v  __attribute__((ext_vector_type(4)));

constexpr int NG = 14, GI = 9, FH = 128, AD = 15;

__device__ __forceinline__ unsigned short f2bf(float f) {
    unsigned u = __builtin_bit_cast(unsigned, f);
    return (unsigned short)((u + 0x7fffu + ((u >> 16) & 1u)) >> 16);
}
__device__ __forceinline__ float bf2f(unsigned short h) {
    return __builtin_bit_cast(float, (unsigned)h << 16);
}
__device__ __forceinline__ f4v load4u(const float* p) {
    f4v v; __builtin_memcpy(&v, p, 16); return v;
}

// Pack W3 (57x128, K pad->64) and W4 (128x30, N pad->32) into per-lane
// B-fragment order: idx = ((kt*NT + nt)*64 + lane)*8 + j, element
// k = kt*32 + (lane>>4)*8 + j, n = nt*16 + (lane&15). hi/lo split-bf16.
__global__ void pack_kernel(const float* __restrict__ W3,
                            const float* __restrict__ W4,
                            unsigned short* __restrict__ pk) {
    unsigned short* W3h = pk;            // 8192 elems
    unsigned short* W3l = pk + 8192;     // 8192
    unsigned short* W4h = pk + 16384;    // 4096
    unsigned short* W4l = pk + 20480;    // 4096
    int t = blockIdx.x * 256 + threadIdx.x;
    if (t < 8192) {
        int j = t & 7, l = (t >> 3) & 63, nt = (t >> 9) & 7, kt = t >> 12;
        int k = kt * 32 + (l >> 4) * 8 + j, n = nt * 16 + (l & 15);
        float v = (k < 57) ? W3[k * FH + n] : 0.f;
        unsigned short h = f2bf(v);
        W3h[t] = h;
        W3l[t] = f2bf(v - bf2f(h));
    }
    if (t < 4096) {
        int j = t & 7, l = (t >> 3) & 63, nt = (t >> 9) & 1, kt = t >> 10;
        int k = kt * 32 + (l >> 4) * 8 + j, n = nt * 16 + (l & 15);
        float v = (n < 30) ? W4[k * 30 + n] : 0.f;
        unsigned short h = f2bf(v);
        W4h[t] = h;
        W4l[t] = f2bf(v - bf2f(h));
    }
}

__global__ __launch_bounds__(256, 4) void actor_fused(
    const float* __restrict__ x,     // [B,126]
    const float* __restrict__ sale,  // [B,1]
    const float* __restrict__ W1,    // [9,16]
    const float* __restrict__ b1,    // [16]
    const float* __restrict__ W2,    // [16,4]
    const float* __restrict__ b2,    // [4]
    const float* __restrict__ b3,    // [128]
    const float* __restrict__ b4,    // [30]
    const unsigned short* __restrict__ pk,
    float* __restrict__ om, float* __restrict__ os)
{
    // sh: 8 KB, aliased in time (phase1/2: s_hi [64][64] bf16 swizzled;
    //     phase3: z_hi [32][128] bf16). xh: x panel as bf16 [64][126].
    __shared__ unsigned short sh[4096];
    __shared__ unsigned short xh[8064];

    const int tid  = threadIdx.x;
    const int wv   = __builtin_amdgcn_readfirstlane(tid >> 6);  // wave 0..3
    const int lane = tid & 63;
    const int r    = lane;                 // row within block (phase 1)
    const int row0 = blockIdx.x * 64;

    // ---- stage x panel (64 rows x 126 f32 = 32 KB) coalesced -> bf16 LDS ----
    {
        const float* xpanel = x + (size_t)row0 * (NG * GI);
        unsigned* xw = (unsigned*)xh;
        #pragma unroll
        for (int j = 0; j < 7; ++j) {
            f4v v = load4u(xpanel + 4 * tid + 1024 * j);
            unsigned w0 = (unsigned)f2bf(v[0]) | ((unsigned)f2bf(v[1]) << 16);
            unsigned w1 = (unsigned)f2bf(v[2]) | ((unsigned)f2bf(v[3]) << 16);
            xw[2 * tid + 512 * j]     = w0;
            xw[2 * tid + 512 * j + 1] = w1;
        }
        if (tid < 224) {   // tail: elements 7168..8063
            f4v v = load4u(xpanel + 4 * tid + 7168);
            unsigned w0 = (unsigned)f2bf(v[0]) | ((unsigned)f2bf(v[1]) << 16);
            unsigned w1 = (unsigned)f2bf(v[2]) | ((unsigned)f2bf(v[3]) << 16);
            xw[2 * tid + 3584] = w0;
            xw[2 * tid + 3585] = w1;
        }
    }
    __syncthreads();

    // ---------------- phase 1: VALU, groups split (4,4,3,3) ----------------
    const int gbase = __builtin_amdgcn_readfirstlane(4 * wv - (wv == 3 ? 1 : 0));
    const f16v* w1v = (const f16v*)W1;
    const f4v*  w2v = (const f4v*)W2;
    const f16v  b1v = *(const f16v*)b1;
    const f4v   b2v = *(const f4v*)b2;

    auto do_group = [&](int gg) {
        const int hb = r * 126 + gg * 9;
        float x0 = bf2f(xh[hb + 0]), x1 = bf2f(xh[hb + 1]), x2 = bf2f(xh[hb + 2]);
        float x3 = bf2f(xh[hb + 3]), x4 = bf2f(xh[hb + 4]), x5 = bf2f(xh[hb + 5]);
        float x6 = bf2f(xh[hb + 6]), x7 = bf2f(xh[hb + 7]), x8 = bf2f(xh[hb + 8]);
        f16v h = b1v;
        h += x0*w1v[0]; h += x1*w1v[1]; h += x2*w1v[2]; h += x3*w1v[3];
        h += x4*w1v[4]; h += x5*w1v[5]; h += x6*w1v[6]; h += x7*w1v[7];
        h += x8*w1v[8];
        h = __builtin_elementwise_max(h, (f16v)0.f);
        f4v s = b2v;
        s += h[0]*w2v[0];  s += h[1]*w2v[1];  s += h[2]*w2v[2];  s += h[3]*w2v[3];
        s += h[4]*w2v[4];  s += h[5]*w2v[5];  s += h[6]*w2v[6];  s += h[7]*w2v[7];
        s += h[8]*w2v[8];  s += h[9]*w2v[9];  s += h[10]*w2v[10]; s += h[11]*w2v[11];
        s += h[12]*w2v[12]; s += h[13]*w2v[13]; s += h[14]*w2v[14]; s += h[15]*w2v[15];
        s = __builtin_elementwise_max(s, (f4v)0.f);
        s4v hi = (s4v){(short)f2bf(s[0]), (short)f2bf(s[1]),
                       (short)f2bf(s[2]), (short)f2bf(s[3])};
        int byt = (r * 128 + gg * 8) ^ ((r & 7) << 4);   // k = gg*4 -> byte gg*8
        *(s4v*)((char*)sh + byt) = hi;
    };
    if (wv < 2) { do_group(gbase+0); do_group(gbase+1); do_group(gbase+2); do_group(gbase+3); }
    else        { do_group(gbase+0); do_group(gbase+1); do_group(gbase+2); }
    if (wv == 3) {
        float sv = sale[row0 + r];
        int byt = (r * 128 + 112) ^ ((r & 7) << 4);      // k=56
        *(unsigned short*)((char*)sh + byt) = f2bf(sv);
        #pragma unroll
        for (int kk = 57; kk < 64; ++kk) {               // zero K-pad
            int bb = (r * 128 + kk * 2) ^ ((r & 7) << 4);
            *(unsigned short*)((char*)sh + bb) = 0;
        }
    }
    __syncthreads();

    // ---------------- phase 2: z[64,128] = s[64,64] @ W3  (MFMA) ----------
    const s8v* W3hv = (const s8v*)pk;
    const s8v* W3lv = (const s8v*)(pk + 8192);
    s8v bh[2][2], bl[2][2];
    #pragma unroll
    for (int kt = 0; kt < 2; ++kt)
        #pragma unroll
        for (int ntl = 0; ntl < 2; ++ntl) {
            int nt = 2 * wv + ntl;
            bh[kt][ntl] = W3hv[(kt * 8 + nt) * 64 + lane];
            bl[kt][ntl] = W3lv[(kt * 8 + nt) * 64 + lane];
        }
    f4v acc[4][2];
    #pragma unroll
    for (int ntl = 0; ntl < 2; ++ntl) {
        float bv = b3[32 * wv + ntl * 16 + (lane & 15)];
        #pragma unroll
        for (int mt = 0; mt < 4; ++mt) acc[mt][ntl] = (f4v){bv, bv, bv, bv};
    }
    #pragma unroll
    for (int kt = 0; kt < 2; ++kt) {
        s8v ah[4];
        #pragma unroll
        for (int mt = 0; mt < 4; ++mt) {
            int rr = mt * 16 + (lane & 15);
            int byt = (rr * 128 + kt * 64 + (lane >> 4) * 16) ^ ((rr & 7) << 4);
            ah[mt] = *(const s8v*)((char*)sh + byt);
        }
        #pragma unroll
        for (int mt = 0; mt < 4; ++mt)
            #pragma unroll
            for (int ntl = 0; ntl < 2; ++ntl) {
                acc[mt][ntl] = __builtin_amdgcn_mfma_f32_16x16x32_bf16(ah[mt], bh[kt][ntl], acc[mt][ntl], 0, 0, 0);
                acc[mt][ntl] = __builtin_amdgcn_mfma_f32_16x16x32_bf16(ah[mt], bl[kt][ntl], acc[mt][ntl], 0, 0, 0);
            }
    }

    // ------- phase 3: out[64,30] = relu(z)[64,128] @ W4, in two row-halves --
    const s8v* W4hv = (const s8v*)(pk + 16384);
    const s8v* W4lv = (const s8v*)(pk + 20480);
    const int mtt  = __builtin_amdgcn_readfirstlane(wv >> 1);
    const int ntt  = __builtin_amdgcn_readfirstlane(wv & 1);
    const int ocol = ntt * 16 + (lane & 15);
    const float b4i = (ocol < 30) ? b4[ocol] : 0.f;

    #pragma unroll
    for (int half = 0; half < 2; ++half) {
        __syncthreads();   // h0: all phase-2 s-reads done; h1: h0 z-reads done
        // stage relu(z) rows [32*half, 32*half+32) as bf16 (hi only)
        #pragma unroll
        for (int mtl = 0; mtl < 2; ++mtl) {
            const int mt = 2 * half + mtl;
            #pragma unroll
            for (int ntl = 0; ntl < 2; ++ntl) {
                const int col = 32 * wv + ntl * 16 + (lane & 15);
                #pragma unroll
                for (int i = 0; i < 4; ++i) {
                    int rowl = mtl * 16 + (lane >> 4) * 4 + i;   // m89 C/D map
                    float v = fmaxf(acc[mt][ntl][i], 0.f);
                    int byt = (rowl * 256 + col * 2) ^ ((rowl & 7) << 4);
                    *(unsigned short*)((char*)sh + byt) = f2bf(v);
                }
            }
        }
        __syncthreads();
        f4v oa = (f4v){b4i, b4i, b4i, b4i};
        #pragma unroll
        for (int kt = 0; kt < 4; ++kt) {
            int rr = mtt * 16 + (lane & 15);
            int byt = (rr * 256 + kt * 64 + (lane >> 4) * 16) ^ ((rr & 7) << 4);
            s8v zh = *(const s8v*)((char*)sh + byt);
            s8v wh = W4hv[(kt * 2 + ntt) * 64 + lane];
            s8v wl = W4lv[(kt * 2 + ntt) * 64 + lane];
            oa = __builtin_amdgcn_mfma_f32_16x16x32_bf16(zh, wh, oa, 0, 0, 0);
            oa = __builtin_amdgcn_mfma_f32_16x16x32_bf16(zh, wl, oa, 0, 0, 0);
        }
        #pragma unroll
        for (int i = 0; i < 4; ++i) {
            int grow = row0 + half * 32 + mtt * 16 + (lane >> 4) * 4 + i;
            float v = oa[i];
            if (ocol < AD) {
                float tc = fminf(fmaxf(v, -20.f), 20.f);
                float e = __expf(2.f * tc);
                om[(size_t)grow * AD + ocol] = (e - 1.f) / (e + 1.f);
            } else if (ocol < 2 * AD) {
                os[(size_t)grow * AD + (ocol - AD)] = __expf(v);
            }
        }
    }
}

extern "C" void kernel_launch(void* const* d_in, const int* in_sizes, int n_in,
                              void* d_out, int out_size, void* d_ws, size_t ws_size,
                              hipStream_t stream) {
    const float* x    = (const float*)d_in[0];
    const float* sale = (const float*)d_in[1];
    const float* W1   = (const float*)d_in[2];
    const float* b1   = (const float*)d_in[3];
    const float* W2   = (const float*)d_in[4];
    const float* b2   = (const float*)d_in[5];
    const float* W3   = (const float*)d_in[6];
    const float* b3   = (const float*)d_in[7];
    const float* W4   = (const float*)d_in[8];
    const float* b4   = (const float*)d_in[9];

    int B = in_sizes[1];                       // sale_predictions is [B,1]
    float* om = (float*)d_out;                 // action_mean flat [B*15]
    float* os = om + (size_t)B * AD;           // action_std  flat [B*15]
    unsigned short* pk = (unsigned short*)d_ws;  // 24576 bf16 = 48 KB

    pack_kernel<<<32, 256, 0, stream>>>(W3, W4, pk);
    actor_fused<<<B / 64, 256, 0, stream>>>(x, sale, W1, b1, W2, b2,
                                            b3, b4, pk, om, os);
}